// Round 1
// baseline (298.420 us; speedup 1.0000x reference)
//
#include <hip/hip_runtime.h>
#include <math.h>

// Problem constants (fixed by setup_inputs)
#define NO_LANE 90
constexpr int Bt  = 32768;
constexpr int Mm  = 6;
constexpr int Tt  = 30;
constexpr int Ll  = 10;
constexpr int NLl = 10;
constexpr int Pp  = 50;

constexpr int WPB  = 4;          // waves (=batches) per block
constexpr int NBLK = Bt / WPB;   // 8192 blocks

__device__ __forceinline__ float smoothl1(float x) {
    float ax = fabsf(x);
    return ax < 1.0f ? 0.5f * x * x : ax - 0.5f;
}

// ---------------------------------------------------------------------------
// has_preds dtype detection: sum the first B*T BYTES of the buffer.
//   bool (1B/elem):  ~0.8*983040           ≈ 786k
//   int32 (4B/elem): first 245760 elems    ≈ 197k
//   fp32  (4B/elem): 1.0f bytes sum to 191 ≈ 37.5M
// => byte layout iff 500k < cnt < 2M; otherwise read as 32-bit words (!=0).
// ---------------------------------------------------------------------------
__global__ void detect_fmt(const unsigned int* __restrict__ hp_words,
                           unsigned int* __restrict__ cnt) {
    unsigned int s = 0;
    const int nw = Bt * Tt / 4; // 245760 words = 983040 bytes (safe for both layouts)
    for (int i = blockIdx.x * blockDim.x + threadIdx.x; i < nw;
         i += gridDim.x * blockDim.x) {
        unsigned int u = hp_words[i];
        s += (u & 0xFFu) + ((u >> 8) & 0xFFu) + ((u >> 16) & 0xFFu) + (u >> 24);
    }
    for (int o = 32; o; o >>= 1) s += __shfl_down(s, o);
    __shared__ unsigned int ls[8];
    int w = threadIdx.x >> 6;
    if ((threadIdx.x & 63) == 0) ls[w] = s;
    __syncthreads();
    if (threadIdx.x == 0) {
        unsigned int tot = 0;
        for (int i = 0; i < (int)(blockDim.x >> 6); ++i) tot += ls[i];
        atomicAdd(cnt, tot);
    }
}

// ---------------------------------------------------------------------------
// Main kernel: one wave per batch.
// ---------------------------------------------------------------------------
__global__ __launch_bounds__(WPB * 64) void pred_loss_main(
    const float* __restrict__ cls, const float* __restrict__ reg,
    const float* __restrict__ lane_cls, const float* __restrict__ gt,
    const float* __restrict__ rot, const float* __restrict__ orig,
    const float* __restrict__ lane_feats, const unsigned char* __restrict__ hp,
    const int* __restrict__ lane_labels, const unsigned int* __restrict__ cnt,
    float* __restrict__ partials, float* __restrict__ accum, int use_partials) {

    __shared__ __align__(16) float sReg[WPB][Mm * Tt * 2]; // 360
    __shared__ __align__(16) float sGt[WPB][Tt * 2];       // 60
    __shared__ __align__(16) float sLW[WPB][Pp * 2];       // 100
    __shared__ float sPart[WPB][8];

    const int w    = threadIdx.x >> 6;
    const int lane = threadIdx.x & 63;
    const int b    = blockIdx.x * WPB + w;

    const unsigned int c = *cnt;
    const bool byte_fmt = (c > 500000u && c < 2000000u);

    // --- has_preds flags, last index, mask (ballot over 64 lanes) ---
    bool has = false;
    if (lane < Tt) {
        int idx = b * Tt + lane;
        has = byte_fmt ? (hp[idx] != 0)
                       : (((const unsigned int*)hp)[idx] != 0u);
    }
    unsigned long long ball = __ballot(has);
    int   last  = 63 - __clzll(ball | 1ULL);          // highest t with has=1
    float maskf = ((ball >> 1) != 0ULL) ? 1.0f : 0.0f; // any has at t>=1
    float n_has = (float)__popcll(ball);
    float hasf  = has ? 1.0f : 0.0f;

    // --- lane label ---
    int   lab    = lane_labels[b];
    bool  valid  = (lab != NO_LANE);
    int   lab_c  = valid ? lab : 0;
    float validf = valid ? 1.0f : 0.0f;

    // --- stage reg / gt into LDS (float4 coalesced-ish) ---
    const float4* regv = (const float4*)(reg + (size_t)b * (Mm * Tt * 2));
    float4* sRegV = (float4*)sReg[w];
    sRegV[lane] = regv[lane];                       // i = 0..63
    if (lane < 26) sRegV[lane + 64] = regv[lane + 64]; // i = 64..89
    if (lane < 15)
        ((float4*)sGt[w])[lane] = ((const float4*)(gt + (size_t)b * (Tt * 2)))[lane];

    // --- selected lane row -> rotate+translate -> LDS ---
    float4 R = *(const float4*)(rot + (size_t)b * 4);  // r00 r01 r10 r11
    float2 O = *(const float2*)(orig + (size_t)b * 2);
    if (lane < 25) {
        float4 ls = ((const float4*)(lane_feats +
                     ((size_t)b * NLl + lab_c) * (Pp * 2)))[lane];
        float4 lw;
        lw.x = ls.x * R.x + ls.y * R.z + O.x;
        lw.y = ls.x * R.y + ls.y * R.w + O.y;
        lw.z = ls.z * R.x + ls.w * R.z + O.x;
        lw.w = ls.z * R.y + ls.w * R.w + O.y;
        ((float4*)sLW[w])[lane] = lw;
    }

    // --- scores for the two softmaxes (register-resident) ---
    float cm = (lane < Mm) ? cls[(size_t)b * Mm + lane] : -INFINITY;
    float lc = (lane < Ll) ? lane_cls[(size_t)b * Ll + lane] : -INFINITY;

    __syncthreads();

    // --- cls_tar: argmin_m sum_{t,c}(reg-gt)^2; lane t holds partial per m ---
    float pm[Mm];
#pragma unroll
    for (int m = 0; m < Mm; ++m) pm[m] = 0.f;
    float gx = 0.f, gy = 0.f;
    if (lane < Tt) {
        gx = sGt[w][2 * lane];
        gy = sGt[w][2 * lane + 1];
#pragma unroll
        for (int m = 0; m < Mm; ++m) {
            float dx = sReg[w][m * 60 + 2 * lane] - gx;
            float dy = sReg[w][m * 60 + 2 * lane + 1] - gy;
            pm[m] = dx * dx + dy * dy;
        }
    }
#pragma unroll
    for (int m = 0; m < Mm; ++m)
#pragma unroll
        for (int o = 32; o; o >>= 1) pm[m] += __shfl_xor(pm[m], o);
    int cls_tar = 0;
    float bestc = pm[0];
#pragma unroll
    for (int m = 1; m < Mm; ++m)
        if (pm[m] < bestc) { bestc = pm[m]; cls_tar = m; } // first-min semantics

    // --- min_idcs: argmin_m endpoint distance (all lanes redundantly, broadcast LDS) ---
    float egx = sGt[w][2 * last], egy = sGt[w][2 * last + 1];
    int   min_i = 0;
    float bd = INFINITY;
#pragma unroll
    for (int m = 0; m < Mm; ++m) {
        float dx = sReg[w][m * 60 + 2 * last] - egx;
        float dy = sReg[w][m * 60 + 2 * last + 1] - egy;
        float d2 = dx * dx + dy * dy;
        if (d2 < bd) { bd = d2; min_i = m; }
    }

    // --- log-softmax NLLs (width-8 / width-16 shuffle reductions) ---
    float mx = cm;
#pragma unroll
    for (int o = 1; o < 8; o <<= 1) mx = fmaxf(mx, __shfl_xor(mx, o));
    float ex = (lane < Mm) ? __expf(cm - mx) : 0.f;
#pragma unroll
    for (int o = 1; o < 8; o <<= 1) ex += __shfl_xor(ex, o);
    float ctar = __shfl(cm, cls_tar);
    float nll  = mx + __logf(ex) - ctar;   // valid on lanes 0..7; lane 0 used

    float mx2 = lc;
#pragma unroll
    for (int o = 1; o < 16; o <<= 1) mx2 = fmaxf(mx2, __shfl_xor(mx2, o));
    float ex2 = (lane < Ll) ? __expf(lc - mx2) : 0.f;
#pragma unroll
    for (int o = 1; o < 16; o <<= 1) ex2 += __shfl_xor(ex2, o);
    float ltar = __shfl(lc, lab_c);
    float lnll = mx2 + __logf(ex2) - ltar; // valid on lanes 0..15; lane 0 used

    // --- reg_loss: smooth_l1(reg_sel - gt) * hasf * maskf ---
    float regl = 0.f;
    float rsx = 0.f, rsy = 0.f;
    if (lane < Tt) {
        rsx = sReg[w][min_i * 60 + 2 * lane];
        rsy = sReg[w][min_i * 60 + 2 * lane + 1];
        regl = (smoothl1(rsx - gx) + smoothl1(rsy - gy)) * hasf * maskf;
    }
#pragma unroll
    for (int o = 32; o; o >>= 1) regl += __shfl_xor(regl, o);

    // --- lane offset loss: lanes 0..29 -> d_reg[t], lanes 32..61 -> d_gt[t] ---
    int t2 = lane & 31;
    float tx = 0.f, ty = 0.f;
    if (t2 < Tt) {
        if (lane < 32) { tx = rsx; ty = rsy; }
        else           { tx = sGt[w][2 * t2]; ty = sGt[w][2 * t2 + 1]; }
    }
    float dmin = INFINITY;
    const float4* lw4 = (const float4*)sLW[w];
#pragma unroll
    for (int j = 0; j < 25; ++j) {   // broadcast LDS reads (same addr all lanes)
        float4 q = lw4[j];
        float dx0 = q.x - tx, dy0 = q.y - ty;
        float dx1 = q.z - tx, dy1 = q.w - ty;
        float d0 = dx0 * dx0 + dy0 * dy0;
        float d1 = dx1 * dx1 + dy1 * dy1;
        dmin = fminf(dmin, fminf(d0, d1));
    }
    float dgt2 = __shfl_down(dmin, 32); // lane t gets gt-min from lane t+32
    float pern = 0.f;
    if (lane < Tt) {
        float dr = sqrtf(dmin), dg = sqrtf(dgt2);
        float diff = dr - dg;
        pern = (dr >= dg) ? diff * hasf : 0.f;
    }
#pragma unroll
    for (int o = 32; o; o >>= 1) pern += __shfl_xor(pern, o);

    // --- per-wave accumulators -> block partials ---
    if (lane == 0) {
        float per = pern / fmaxf(n_has, 1.0f);
        sPart[w][0] = nll * maskf;               // cls_loss numerator
        sPart[w][1] = maskf;                     // cls_loss denominator
        sPart[w][2] = regl;                      // reg_loss
        sPart[w][3] = maskf * n_has;             // num_reg
        sPart[w][4] = lnll * (float)(lab_c + 1) * validf; // lane_cls_loss
        sPart[w][5] = validf;                    // num_lane_cls
        sPart[w][6] = per * validf * maskf;      // lane_off_loss
        sPart[w][7] = validf * maskf;            // num_lane_off
    }
    __syncthreads();
    if (threadIdx.x < 8) {
        float s = sPart[0][threadIdx.x] + sPart[1][threadIdx.x] +
                  sPart[2][threadIdx.x] + sPart[3][threadIdx.x];
        if (use_partials)
            partials[(size_t)blockIdx.x * 8 + threadIdx.x] = s;
        else
            atomicAdd(accum + threadIdx.x, s);
    }
}

// ---------------------------------------------------------------------------
// Final reduction over per-block partials + epilogue division.
// ---------------------------------------------------------------------------
__global__ void finalize_k(const float* __restrict__ partials,
                           float* __restrict__ out, int nb) {
    int c  = threadIdx.x & 7;
    int i0 = threadIdx.x >> 3;
    float s = 0.f;
    for (int k = i0; k < nb; k += 32) s += partials[(size_t)k * 8 + c];
    __shared__ float red[256];
    red[threadIdx.x] = s;
    __syncthreads();
    if (threadIdx.x < 8) {
        float tot = 0.f;
        for (int i = 0; i < 32; ++i) tot += red[i * 8 + threadIdx.x];
        red[threadIdx.x] = tot; // each thread only touches column c: no race
    }
    __syncthreads();
    if (threadIdx.x == 0) {
        out[0] = red[0] / fmaxf(red[1], 1.0f);
        out[1] = 1.0f;
        out[2] = red[2];
        out[3] = red[3];
        out[4] = red[4];
        out[5] = red[5];
        out[6] = red[6];
        out[7] = red[7];
    }
}

extern "C" void kernel_launch(void* const* d_in, const int* in_sizes, int n_in,
                              void* d_out, int out_size, void* d_ws, size_t ws_size,
                              hipStream_t stream) {
    const float* cls        = (const float*)d_in[0];
    const float* reg        = (const float*)d_in[1];
    const float* lane_cls   = (const float*)d_in[2];
    const float* gt         = (const float*)d_in[3];
    const float* rot        = (const float*)d_in[4];
    const float* orig       = (const float*)d_in[5];
    const float* lane_feats = (const float*)d_in[6];
    const unsigned char* hp = (const unsigned char*)d_in[7];
    const int* lane_labels  = (const int*)d_in[8];
    float* out = (float*)d_out;

    unsigned int* cnt = (unsigned int*)d_ws;                 // [0,4): detect counter
    float* accum      = (float*)((char*)d_ws + 16);          // [16,48): atomic fallback
    float* partials   = (float*)((char*)d_ws + 256);         // [256, ...): block partials
    size_t need = 256 + (size_t)NBLK * 8 * sizeof(float);
    int use_partials = (ws_size >= need) ? 1 : 0;

    hipMemsetAsync(d_ws, 0, 64, stream);
    detect_fmt<<<256, 256, 0, stream>>>((const unsigned int*)hp, cnt);
    pred_loss_main<<<NBLK, WPB * 64, 0, stream>>>(
        cls, reg, lane_cls, gt, rot, orig, lane_feats, hp, lane_labels, cnt,
        partials, accum, use_partials);
    finalize_k<<<1, 256, 0, stream>>>(use_partials ? partials : accum, out,
                                      use_partials ? NBLK : 1);
}

// Round 2
// 238.142 us; speedup vs baseline: 1.2531x; 1.2531x over previous
//
#include <hip/hip_runtime.h>
#include <math.h>

// Problem constants (fixed by setup_inputs)
#define NO_LANE 90
constexpr int Bt  = 32768;
constexpr int Mm  = 6;
constexpr int Tt  = 30;
constexpr int Ll  = 10;
constexpr int NLl = 10;
constexpr int Pp  = 50;

constexpr int BPB  = 8;          // batches per block (half-wave each)
constexpr int NBLK = Bt / BPB;   // 4096 blocks

// LDS row pads (floats), keep 16B alignment of rows
constexpr int RPAD = 368;  // >= 360
constexpr int GPAD = 64;   // >= 60
constexpr int LPAD = 104;  // >= 100

__device__ __forceinline__ float smoothl1(float x) {
    float ax = fabsf(x);
    return ax < 1.0f ? 0.5f * x * x : ax - 0.5f;
}

// ---------------------------------------------------------------------------
// has_preds dtype detection on a 4 KB sample (first 1024 words).
//   bool  (1B/elem): ~0.8*4096 bytes of 1       => ~3.3k   (byte layout)
//   int32 (4B/elem): ~0.8*1024 ones in LSB      => ~0.8k   (word layout)
//   fp32  (4B/elem): 1.0f bytes sum 191/elem    => ~156k   (word layout, !=0)
// byte layout iff 2000 < cnt < 10000.
// ---------------------------------------------------------------------------
__global__ void detect_fmt(const unsigned int* __restrict__ hp_words,
                           unsigned int* __restrict__ cnt) {
    unsigned int s = 0;
    for (int i = threadIdx.x; i < 1024; i += 256) {
        unsigned int u = hp_words[i];
        s += (u & 0xFFu) + ((u >> 8) & 0xFFu) + ((u >> 16) & 0xFFu) + (u >> 24);
    }
    for (int o = 32; o; o >>= 1) s += __shfl_down(s, o);
    if ((threadIdx.x & 63) == 0) atomicAdd(cnt, s);
}

// ---------------------------------------------------------------------------
// Main kernel: one HALF-WAVE (32 lanes) per batch, 8 batches / 256-block.
// All cross-lane reductions use xor offsets <=16 so they never cross the
// 32-lane half; every DS instruction serves two batches.
// ---------------------------------------------------------------------------
__global__ __launch_bounds__(256) void pred_loss_main(
    const float* __restrict__ cls, const float* __restrict__ reg,
    const float* __restrict__ lane_cls, const float* __restrict__ gt,
    const float* __restrict__ rot, const float* __restrict__ orig,
    const float* __restrict__ lane_feats, const unsigned char* __restrict__ hp,
    const int* __restrict__ lane_labels, const unsigned int* __restrict__ cnt,
    float* __restrict__ partials, float* __restrict__ accum, int use_partials) {

    __shared__ __align__(16) float sReg[BPB][RPAD];
    __shared__ __align__(16) float sGt[BPB][GPAD];
    __shared__ __align__(16) float sLW[BPB][LPAD];
    __shared__ float sPart[BPB][8];

    const int tid = threadIdx.x;
    const int sb  = tid >> 5;          // sub-batch in block (0..7)
    const int l   = tid & 31;          // lane within half-wave
    const int h   = (tid >> 5) & 1;    // which half of my 64-wave
    const int b   = blockIdx.x * BPB + sb;

    const unsigned int c = *cnt;
    const bool byte_fmt = (c > 2000u && c < 10000u);

    // --- has_preds flags, last index, mask (per-half ballot) ---
    bool has = false;
    if (l < Tt) {
        int idx = b * Tt + l;
        has = byte_fmt ? (hp[idx] != 0)
                       : (((const unsigned int*)hp)[idx] != 0u);
    }
    unsigned long long ball = __ballot(has);
    unsigned int mmask = (unsigned int)(ball >> (h * 32));
    int   last  = 31 - __clz((int)(mmask | 1u));     // highest t with has=1
    float maskf = (mmask >> 1) ? 1.0f : 0.0f;        // any has at t>=1
    float n_has = (float)__popc((int)mmask);
    float hasf  = has ? 1.0f : 0.0f;

    // --- lane label ---
    int   lab    = lane_labels[b];
    bool  valid  = (lab != NO_LANE);
    int   lab_c  = valid ? lab : 0;
    float validf = valid ? 1.0f : 0.0f;

    // --- stage reg / gt into LDS (float4, coalesced: adjacent halves = adjacent batches) ---
    const float4* regv = (const float4*)(reg + (size_t)b * (Mm * Tt * 2));
    float4* sRegV = (float4*)&sReg[sb][0];
    sRegV[l]      = regv[l];
    sRegV[l + 32] = regv[l + 32];
    if (l < 26) sRegV[l + 64] = regv[l + 64];
    if (l < 15)
        ((float4*)&sGt[sb][0])[l] = ((const float4*)(gt + (size_t)b * (Tt * 2)))[l];

    // --- selected lane row -> rotate+translate -> LDS ---
    float4 R = *(const float4*)(rot + (size_t)b * 4);  // r00 r01 r10 r11
    float2 O = *(const float2*)(orig + (size_t)b * 2);
    if (l < 25) {
        float4 ls = ((const float4*)(lane_feats +
                     ((size_t)b * NLl + lab_c) * (Pp * 2)))[l];
        float4 lw;
        lw.x = ls.x * R.x + ls.y * R.z + O.x;
        lw.y = ls.x * R.y + ls.y * R.w + O.y;
        lw.z = ls.z * R.x + ls.w * R.z + O.x;
        lw.w = ls.z * R.y + ls.w * R.w + O.y;
        ((float4*)&sLW[sb][0])[l] = lw;
    }

    // --- scores for the two softmaxes (register-resident; lanes 0..5 / 0..9) ---
    float cm = (l < Mm) ? cls[(size_t)b * Mm + l] : -INFINITY;
    float lc = (l < Ll) ? lane_cls[(size_t)b * Ll + l] : -INFINITY;

    __syncthreads();

    // --- cls_tar: argmin_m sum_{t,c}(reg-gt)^2; lane t holds partial per m ---
    float pm[Mm];
#pragma unroll
    for (int m = 0; m < Mm; ++m) pm[m] = 0.f;
    float gx = 0.f, gy = 0.f;
    if (l < Tt) {
        gx = sGt[sb][2 * l];
        gy = sGt[sb][2 * l + 1];
#pragma unroll
        for (int m = 0; m < Mm; ++m) {
            float dx = sReg[sb][m * 60 + 2 * l] - gx;
            float dy = sReg[sb][m * 60 + 2 * l + 1] - gy;
            pm[m] = dx * dx + dy * dy;
        }
    }
#pragma unroll
    for (int m = 0; m < Mm; ++m)
#pragma unroll
        for (int o = 16; o; o >>= 1) pm[m] += __shfl_xor(pm[m], o);
    int cls_tar = 0;
    float bestc = pm[0];
#pragma unroll
    for (int m = 1; m < Mm; ++m)
        if (pm[m] < bestc) { bestc = pm[m]; cls_tar = m; } // first-min semantics

    // --- min_idcs: argmin_m endpoint distance (uniform per half, broadcast LDS) ---
    float egx = sGt[sb][2 * last], egy = sGt[sb][2 * last + 1];
    int   min_i = 0;
    float bd = INFINITY;
#pragma unroll
    for (int m = 0; m < Mm; ++m) {
        float dx = sReg[sb][m * 60 + 2 * last] - egx;
        float dy = sReg[sb][m * 60 + 2 * last + 1] - egy;
        float d2 = dx * dx + dy * dy;
        if (d2 < bd) { bd = d2; min_i = m; }
    }

    // --- log-softmax NLLs (xor-tree over 8 / 16 lanes within the half) ---
    float mx = cm;
#pragma unroll
    for (int o = 4; o; o >>= 1) mx = fmaxf(mx, __shfl_xor(mx, o));
    float ex = (l < Mm) ? __expf(cm - mx) : 0.f;
#pragma unroll
    for (int o = 4; o; o >>= 1) ex += __shfl_xor(ex, o);
    float ctar = __shfl(cm, cls_tar + h * 32);
    float nll  = mx + __logf(ex) - ctar;   // valid on lanes 0..7 of half

    float mx2 = lc;
#pragma unroll
    for (int o = 8; o; o >>= 1) mx2 = fmaxf(mx2, __shfl_xor(mx2, o));
    float ex2 = (l < Ll) ? __expf(lc - mx2) : 0.f;
#pragma unroll
    for (int o = 8; o; o >>= 1) ex2 += __shfl_xor(ex2, o);
    float ltar = __shfl(lc, lab_c + h * 32);
    float lnll = mx2 + __logf(ex2) - ltar; // valid on lanes 0..15 of half

    // --- reg_loss: smooth_l1(reg_sel - gt) * hasf * maskf ---
    float regl = 0.f;
    float rsx = 0.f, rsy = 0.f;
    if (l < Tt) {
        rsx = sReg[sb][min_i * 60 + 2 * l];
        rsy = sReg[sb][min_i * 60 + 2 * l + 1];
        regl = (smoothl1(rsx - gx) + smoothl1(rsy - gy)) * hasf * maskf;
    }
#pragma unroll
    for (int o = 16; o; o >>= 1) regl += __shfl_xor(regl, o);

    // --- lane offset loss: fused d_reg/d_gt point-min, one broadcast read/j ---
    float dminR = INFINITY, dminG = INFINITY;
    const float4* lw4 = (const float4*)&sLW[sb][0];
#pragma unroll
    for (int j = 0; j < 25; ++j) {   // uniform addr per half: broadcast, 2-addr/wave
        float4 q = lw4[j];
        float ax0 = q.x - rsx, ay0 = q.y - rsy;
        float ax1 = q.z - rsx, ay1 = q.w - rsy;
        dminR = fminf(dminR, fminf(ax0 * ax0 + ay0 * ay0, ax1 * ax1 + ay1 * ay1));
        float bx0 = q.x - gx, by0 = q.y - gy;
        float bx1 = q.z - gx, by1 = q.w - gy;
        dminG = fminf(dminG, fminf(bx0 * bx0 + by0 * by0, bx1 * bx1 + by1 * by1));
    }
    float pern = 0.f;
    if (l < Tt) {
        float dr = sqrtf(dminR), dg = sqrtf(dminG);
        pern = (dr >= dg) ? (dr - dg) * hasf : 0.f;
    }
#pragma unroll
    for (int o = 16; o; o >>= 1) pern += __shfl_xor(pern, o);

    // --- per-half accumulators -> block partials ---
    if (l == 0) {
        float per = pern / fmaxf(n_has, 1.0f);
        sPart[sb][0] = nll * maskf;               // cls_loss numerator
        sPart[sb][1] = maskf;                     // cls_loss denominator
        sPart[sb][2] = regl;                      // reg_loss
        sPart[sb][3] = maskf * n_has;             // num_reg
        sPart[sb][4] = lnll * (float)(lab_c + 1) * validf; // lane_cls_loss
        sPart[sb][5] = validf;                    // num_lane_cls
        sPart[sb][6] = per * validf * maskf;      // lane_off_loss
        sPart[sb][7] = validf * maskf;            // num_lane_off
    }
    __syncthreads();
    if (tid < 8) {
        float s = 0.f;
#pragma unroll
        for (int k = 0; k < BPB; ++k) s += sPart[k][tid];
        if (use_partials)
            partials[(size_t)blockIdx.x * 8 + tid] = s;
        else
            atomicAdd(accum + tid, s);
    }
}

// ---------------------------------------------------------------------------
// Final reduction over per-block partials + epilogue division.
// ---------------------------------------------------------------------------
__global__ __launch_bounds__(1024) void finalize_k(const float* __restrict__ partials,
                                                   float* __restrict__ out, int nb) {
    int c  = threadIdx.x & 7;
    int i0 = threadIdx.x >> 3;   // 0..127
    float s = 0.f;
    for (int k = i0; k < nb; k += 128) s += partials[(size_t)k * 8 + c];
    __shared__ float red[1024];
    red[threadIdx.x] = s;
    __syncthreads();
    for (int off = 512; off >= 8; off >>= 1) {
        if ((int)threadIdx.x < off) red[threadIdx.x] += red[threadIdx.x + off];
        __syncthreads();
    }
    if (threadIdx.x == 0) {
        out[0] = red[0] / fmaxf(red[1], 1.0f);
        out[1] = 1.0f;
        out[2] = red[2];
        out[3] = red[3];
        out[4] = red[4];
        out[5] = red[5];
        out[6] = red[6];
        out[7] = red[7];
    }
}

extern "C" void kernel_launch(void* const* d_in, const int* in_sizes, int n_in,
                              void* d_out, int out_size, void* d_ws, size_t ws_size,
                              hipStream_t stream) {
    const float* cls        = (const float*)d_in[0];
    const float* reg        = (const float*)d_in[1];
    const float* lane_cls   = (const float*)d_in[2];
    const float* gt         = (const float*)d_in[3];
    const float* rot        = (const float*)d_in[4];
    const float* orig       = (const float*)d_in[5];
    const float* lane_feats = (const float*)d_in[6];
    const unsigned char* hp = (const unsigned char*)d_in[7];
    const int* lane_labels  = (const int*)d_in[8];
    float* out = (float*)d_out;

    unsigned int* cnt = (unsigned int*)d_ws;                 // [0,4): detect counter
    float* accum      = (float*)((char*)d_ws + 16);          // [16,48): atomic fallback
    float* partials   = (float*)((char*)d_ws + 256);         // [256, ...): block partials
    size_t need = 256 + (size_t)NBLK * 8 * sizeof(float);
    int use_partials = (ws_size >= need) ? 1 : 0;

    hipMemsetAsync(d_ws, 0, 64, stream);
    detect_fmt<<<1, 256, 0, stream>>>((const unsigned int*)hp, cnt);
    pred_loss_main<<<NBLK, 256, 0, stream>>>(
        cls, reg, lane_cls, gt, rot, orig, lane_feats, hp, lane_labels, cnt,
        partials, accum, use_partials);
    finalize_k<<<1, 1024, 0, stream>>>(use_partials ? partials : accum, out,
                                       use_partials ? NBLK : 1);
}